// Round 1
// 574.769 us; speedup vs baseline: 1.1349x; 1.1349x over previous
//
#include <hip/hip_runtime.h>
#include <hip/hip_bf16.h>

// Correlation (FlowNetC/PWC) cost volume via bf16 MFMA banded-GEMM.
// B=4 C=128 H=W=192, disp grid 21x21 (stride 2), K=3 window, PAD=3.
// corr[b,dyi,t,y,x] = sum_c in1[c,y+17,x+17] * in2[c,y+17+dy,x+17+2t-20]
// out[b,dyi*21+t,i,j] = (1/1152) * sum_{3x3} corr[...]
//
// Round-2 structure: (0) fp32->bf16 + transpose to channels-last [b][y][x][c],
// (1) MFMA corr with A/B fragments loaded DIRECTLY from global (no A/B LDS
// staging; only a 5.7KB double-buffered scatter tile, 1 barrier/dyi),
// (2) 3x3 window sum. Fallback to round-1 fp32 kernel if ws too small.

#define C_    128
#define H_    192
#define W_    192
#define HW_   36864
#define NE_   18874368            // elems per input (4*128*192*192)
#define CORR_E 44036496           // 4*441*158*158
#define WS_NEED 163570464ull      // 2*NE_*2 + CORR_E*2 bytes

typedef __attribute__((ext_vector_type(8))) short short8;
typedef __attribute__((ext_vector_type(4))) float floatx4;

__device__ __forceinline__ float bf2f(ushort h) {
    uint u = ((uint)h) << 16;
    return __builtin_bit_cast(float, u);
}
__device__ __forceinline__ ushort f2bf(float f) {
    __hip_bfloat16 hb = __float2bfloat16(f);
    return *(ushort*)&hb;
}

// ---------------- kernel 0: fp32 [b][c][y][x] -> bf16 channels-last [b][y][x][c] ----------------
// Tile: 128 c x 64 hw positions (192%64==0 so a tile never crosses a y row).
// LDS fp32 tile stride 65 (load writes 2-way-free, read 4-way — streaming kernel).
__global__ __launch_bounds__(256)
void cvt_t_kernel(const float* __restrict__ a, const float* __restrict__ b,
                  ushort* __restrict__ dst0) {
    __shared__ float tile[128 * 65];
    const float* src = blockIdx.z ? b : a;
    ushort* dst = dst0 + (size_t)blockIdx.z * NE_;
    const int bb = blockIdx.y;
    const int hw0 = blockIdx.x * 64;
    const int t = threadIdx.x;
    const int xr = (t & 15) * 4;
    const int c0 = t >> 4;
    const float* sbase = src + (size_t)bb * C_ * HW_ + hw0;
#pragma unroll
    for (int pass = 0; pass < 8; ++pass) {
        const int c = c0 + 16 * pass;
        float4 v = *(const float4*)(sbase + (size_t)c * HW_ + xr);
        float* lp = &tile[c * 65 + xr];
        lp[0] = v.x; lp[1] = v.y; lp[2] = v.z; lp[3] = v.w;
    }
    __syncthreads();
    ushort* obase = dst + ((size_t)bb * HW_ + hw0) * 128;
#pragma unroll
    for (int pass = 0; pass < 4; ++pass) {
        const int u = t + 256 * pass;           // 1024 tasks: x (64) x oc (16)
        const int x = u >> 4, oc = u & 15;
        uint w[4];
#pragma unroll
        for (int k = 0; k < 4; ++k) {
            const float f0 = tile[(oc * 8 + 2 * k) * 65 + x];
            const float f1 = tile[(oc * 8 + 2 * k + 1) * 65 + x];
            w[k] = (uint)f2bf(f0) | ((uint)f2bf(f1) << 16);
        }
        uint4 o; o.x = w[0]; o.y = w[1]; o.z = w[2]; o.w = w[3];
        *(uint4*)(obase + (size_t)x * 128 + oc * 8) = o;
    }
}

// ---------------- kernel 1: MFMA corr, fragments direct from global ----------------
// Block: 32-wide j tile, 2 same-parity corr rows {ybase, ybase+2}, z = b*2+q.
// 4 waves = (yrow, p=x-parity). Per dyi: 12 x 16B B-frag loads (L2), 12 MFMA,
// scatter -> ctile[dyi&1], ONE barrier, coalesced store. Zero-masking of
// OOB rows/cols implements the reference's zero-padding exactly.
__global__ __launch_bounds__(256, 6)
void corr_mfma(const ushort* __restrict__ in1t, const ushort* __restrict__ in2t,
               ushort* __restrict__ corrw) {
    __shared__ ushort ctile[2][1428];   // [slot][t*68 + yrow*34 + x], x in [0,32)
    const int tid = threadIdx.x;
    const int j0 = blockIdx.x * 32;
    const int ytile = blockIdx.y;
    const int zz = blockIdx.z;
    const int b = zz >> 1, q = zz & 1;
    const int ybase = q + 4 * ytile;    // corr row of yrow 0 (covers 0..159)
    const int lane = tid & 63, wav = tid >> 6;
    const int yrow = wav >> 1, p = wav & 1;
    const int mn = lane & 15, quad = lane >> 4;

    // A fragments direct from global: in1t[b, ybase+2yrow+17, j0+17+2mn+p, c]
    const int arow = ybase + 2 * yrow + 17;          // always < 192
    const int ax = j0 + 17 + 2 * mn + p;             // always < 192
    const ushort* aptr = in1t + ((size_t)((b * H_ + arow) * W_ + ax)) * C_ + quad * 8;
    short8 afr[4];
#pragma unroll
    for (int kb = 0; kb < 4; ++kb) afr[kb] = *(const short8*)(aptr + kb * 32);

    // B base pointers per u3 at dyi=0: in2t[b, ybY+2dyi, j0-3+p+2s, c], s = u3*16+mn
    const int ybY = ybase + 2 * yrow - 3;
    const ushort* bptr[3];
    bool colok[3];
#pragma unroll
    for (int u3 = 0; u3 < 3; ++u3) {
        const int xp = j0 - 3 + p + 2 * (u3 * 16 + mn);
        colok[u3] = ((unsigned)xp < (unsigned)W_);   // OOB col => in2 zero-pad
        bptr[u3] = in2t + (ptrdiff_t)((b * H_ + ybY) * W_ + xp) * C_ + quad * 8;
    }

    const short8 z8 = {0, 0, 0, 0, 0, 0, 0, 0};
    const size_t planebase = (size_t)b * 441;

    for (int dyi = 0; dyi < 21; ++dyi) {
        floatx4 acc[3];
#pragma unroll
        for (int u3 = 0; u3 < 3; ++u3) acc[u3] = (floatx4){0.f, 0.f, 0.f, 0.f};
        const bool rowok = ((unsigned)(ybY + 2 * dyi) < (unsigned)H_);  // wave-uniform
        if (rowok) {
#pragma unroll
            for (int u3 = 0; u3 < 3; ++u3) {
                short8 b0 = z8, b1 = z8, b2 = z8, b3 = z8;
                if (colok[u3]) {                     // per-lane mask, loads only
                    const ushort* bp = bptr[u3];
                    b0 = *(const short8*)(bp);
                    b1 = *(const short8*)(bp + 32);
                    b2 = *(const short8*)(bp + 64);
                    b3 = *(const short8*)(bp + 96);
                }
                // MFMA outside the divergent region: full-exec, zeroed frags
                acc[u3] = __builtin_amdgcn_mfma_f32_16x16x32_bf16(afr[0], b0, acc[u3], 0, 0, 0);
                acc[u3] = __builtin_amdgcn_mfma_f32_16x16x32_bf16(afr[1], b1, acc[u3], 0, 0, 0);
                acc[u3] = __builtin_amdgcn_mfma_f32_16x16x32_bf16(afr[2], b2, acc[u3], 0, 0, 0);
                acc[u3] = __builtin_amdgcn_mfma_f32_16x16x32_bf16(afr[3], b3, acc[u3], 0, 0, 0);
            }
        }
#pragma unroll
        for (int u3 = 0; u3 < 3; ++u3) bptr[u3] += 2 * W_ * C_;   // +2 in2 rows

        // scatter C frags: (mr = quad*4+v, s = u3*16+mn) -> t = s-mr, x = 2mr+p
        ushort* ct = &ctile[dyi & 1][0];
#pragma unroll
        for (int u3 = 0; u3 < 3; ++u3) {
#pragma unroll
            for (int v = 0; v < 4; ++v) {
                const int mr = quad * 4 + v;
                const int t = u3 * 16 + mn - mr;
                if (t >= 0 && t <= 20)
                    ct[t * 68 + yrow * 34 + 2 * mr + p] = f2bf(acc[u3][v]);
            }
        }
        __syncthreads();   // scatter complete; also fences slot reuse (2-apart)
        // coalesced store of corr tile (dword = 2 bf16)
#pragma unroll
        for (int it = 0; it < 3; ++it) {
            const int idx = tid + it * 256;
            if (idx < 672) {
                const int t = idx >> 5, rem = idx & 31;
                const int yy = rem >> 4, x2 = (rem & 15) << 1;
                const uint val = *(const uint*)(ct + t * 68 + yy * 34 + x2);
                const int Y = ybase + 2 * yy, X = j0 + x2;
                if (Y < 158 && X < 158) {
                    const size_t off = ((planebase + (size_t)(dyi * 21 + t)) * 158 + Y) * 158 + X;
                    *(uint*)(corrw + off) = val;
                }
            }
        }
    }
}

// ---------------- kernel 2: 3x3 window sum (16 out rows / block) ----------------
__global__ __launch_bounds__(256)
void window_kernel(const ushort* __restrict__ corrw, float* __restrict__ out) {
    __shared__ uint wsl[1440];   // 18 rows x 80 dwords (160 bf16 cols)
    const int tid = threadIdx.x;
    const int i0 = blockIdx.x * 16;
    const int plane = blockIdx.y;
    const ushort* cp = corrw + (size_t)plane * 24964;
    for (int task = tid; task < 1440; task += 256) {
        const int r = task / 80;
        const int dc = task - r * 80;
        const int row = i0 + r;
        if (dc < 79 && row < 158)
            wsl[task] = *(const uint*)(cp + row * 158 + dc * 2);
    }
    __syncthreads();
    if (tid < 156) {
        const ushort* cl = (const ushort*)wsl;
        float S[18];
#pragma unroll
        for (int r = 0; r < 18; ++r) {
            const ushort* rp = cl + r * 160 + tid;
            S[r] = bf2f(rp[0]) + bf2f(rp[1]) + bf2f(rp[2]);
        }
        const float sc = 1.f / 1152.f;
#pragma unroll
        for (int r = 0; r < 16; ++r) {
            const int row = i0 + r;
            if (row < 156)
                out[(size_t)plane * 24336 + (size_t)row * 156 + tid] =
                    (S[r] + S[r + 1] + S[r + 2]) * sc;
        }
    }
}

// ---------------- fallback (round-1 fp32 kernel) ----------------
#define OUT_HW 156
#define NDISP 21
#define TILE_OUT 14
#define TILE_CORR 16
#define S2W 56
#define NT 256

__global__ __launch_bounds__(NT, 4)
void corr_fallback(const float* __restrict__ in1, const float* __restrict__ in2,
                   float* __restrict__ out) {
    __shared__ float s2s[TILE_CORR * S2W];
    __shared__ float corrs[NDISP * TILE_CORR * TILE_CORR];
    const int tid = threadIdx.x;
    const int tx = tid & 15;
    const int ty = tid >> 4;
    const int tj = blockIdx.x;
    const int ti = blockIdx.y;
    const int z = blockIdx.z;
    const int b = z / NDISP;
    const int dyi = z - b * NDISP;
    const int dy = 2 * dyi - 20;
    const int y0 = ti * TILE_OUT;
    const int x0 = tj * TILE_OUT;
    const int y = y0 + ty;
    const int x = x0 + tx;
    float acc[NDISP];
#pragma unroll
    for (int d = 0; d < NDISP; ++d) acc[d] = 0.f;
    const float* p1 = in1 + (size_t)b * C_ * HW_ + (size_t)(y + 17) * W_ + (x + 17);
    const float* p2base = in2 + (size_t)b * C_ * HW_;
    for (int c = 0; c < C_; ++c) {
        const float a = p1[(size_t)c * HW_];
        const float* p2 = p2base + (size_t)c * HW_;
        for (int idx = tid; idx < TILE_CORR * S2W; idx += NT) {
            const int r = idx / S2W;
            const int cc = idx - r * S2W;
            const int gr = y0 + r + 17 + dy;
            const int gc = x0 + cc - 3;
            float v = 0.f;
            if ((unsigned)gr < H_ && (unsigned)gc < W_) v = p2[gr * W_ + gc];
            s2s[idx] = v;
        }
        __syncthreads();
        const float* srow = &s2s[ty * S2W + tx];
#pragma unroll
        for (int d = 0; d < NDISP; ++d) acc[d] += a * srow[2 * d];
        __syncthreads();
    }
#pragma unroll
    for (int d = 0; d < NDISP; ++d)
        corrs[d * (TILE_CORR * TILE_CORR) + tid] = acc[d];
    __syncthreads();
    const float scale = 1.f / 1152.f;
    for (int o = tid; o < NDISP * TILE_OUT * TILE_OUT; o += NT) {
        const int d = o / (TILE_OUT * TILE_OUT);
        const int rem = o - d * (TILE_OUT * TILE_OUT);
        const int i = rem / TILE_OUT;
        const int j = rem - i * TILE_OUT;
        const float* cpt = &corrs[d * (TILE_CORR * TILE_CORR) + i * TILE_CORR + j];
        const float s = cpt[0] + cpt[1] + cpt[2]
                      + cpt[16] + cpt[17] + cpt[18]
                      + cpt[32] + cpt[33] + cpt[34];
        const int ig = y0 + i;
        const int jg = x0 + j;
        if (ig < OUT_HW && jg < OUT_HW) {
            const size_t oidx = (((size_t)b * (NDISP * NDISP) + (size_t)dyi * NDISP + d)
                                 * OUT_HW + ig) * OUT_HW + jg;
            out[oidx] = s * scale;
        }
    }
}

extern "C" void kernel_launch(void* const* d_in, const int* in_sizes, int n_in,
                              void* d_out, int out_size, void* d_ws, size_t ws_size,
                              hipStream_t stream) {
    const float* in1 = (const float*)d_in[0];
    const float* in2 = (const float*)d_in[1];
    float* out = (float*)d_out;

    if (ws_size >= WS_NEED) {
        ushort* wsp = (ushort*)d_ws;
        ushort* in1t = wsp;
        ushort* in2t = wsp + (size_t)NE_;
        ushort* corrw = wsp + (size_t)2 * NE_;
        cvt_t_kernel<<<dim3(576, 4, 2), 256, 0, stream>>>(in1, in2, wsp);
        corr_mfma<<<dim3(5, 40, 8), 256, 0, stream>>>(in1t, in2t, corrw);
        window_kernel<<<dim3(10, 1764), 256, 0, stream>>>(corrw, out);
    } else {
        corr_fallback<<<dim3(12, 12, 84), 256, 0, stream>>>(in1, in2, out);
    }
}

// Round 2
// 506.583 us; speedup vs baseline: 1.2876x; 1.1346x over previous
//
#include <hip/hip_runtime.h>
#include <hip/hip_bf16.h>

// Correlation (FlowNetC/PWC) cost volume via bf16 MFMA banded-GEMM.
// B=4 C=128 H=W=192, disp grid 21x21 (stride 2), K=3 window, PAD=3.
// corr[b,dyi,t,y,x] = sum_c in1[c,y+17,x+17] * in2[c,y+17+dy,x+17+2t-20]
// out[b,dyi*21+t,i,j] = (1/1152) * sum_{3x3} corr[...]
//
// Round-3 structure: (0) fp32->bf16 + transpose to channels-last [b][y][x][c],
// (1) MFMA corr, fragments direct from global. Per block: 4 corr rows
// (2 per wave), dead-band (s>36) loads masked, XCD-pinned (b,q) swizzle.
// (2) 3x3 window sum. Fallback to round-1 fp32 kernel if ws too small.

#define C_    128
#define H_    192
#define W_    192
#define HW_   36864
#define NE_   18874368            // elems per input (4*128*192*192)
#define CORR_E 44036496           // 4*441*158*158
#define WS_NEED 163570464ull      // 2*NE_*2 + CORR_E*2 bytes

typedef __attribute__((ext_vector_type(8))) short short8;
typedef __attribute__((ext_vector_type(4))) float floatx4;

__device__ __forceinline__ float bf2f(ushort h) {
    uint u = ((uint)h) << 16;
    return __builtin_bit_cast(float, u);
}
__device__ __forceinline__ ushort f2bf(float f) {
    __hip_bfloat16 hb = __float2bfloat16(f);
    return *(ushort*)&hb;
}

// ---------------- kernel 0: fp32 [b][c][y][x] -> bf16 channels-last [b][y][x][c] ----------------
__global__ __launch_bounds__(256)
void cvt_t_kernel(const float* __restrict__ a, const float* __restrict__ b,
                  ushort* __restrict__ dst0) {
    __shared__ float tile[128 * 65];
    const float* src = blockIdx.z ? b : a;
    ushort* dst = dst0 + (size_t)blockIdx.z * NE_;
    const int bb = blockIdx.y;
    const int hw0 = blockIdx.x * 64;
    const int t = threadIdx.x;
    const int xr = (t & 15) * 4;
    const int c0 = t >> 4;
    const float* sbase = src + (size_t)bb * C_ * HW_ + hw0;
#pragma unroll
    for (int pass = 0; pass < 8; ++pass) {
        const int c = c0 + 16 * pass;
        float4 v = *(const float4*)(sbase + (size_t)c * HW_ + xr);
        float* lp = &tile[c * 65 + xr];
        lp[0] = v.x; lp[1] = v.y; lp[2] = v.z; lp[3] = v.w;
    }
    __syncthreads();
    ushort* obase = dst + ((size_t)bb * HW_ + hw0) * 128;
#pragma unroll
    for (int pass = 0; pass < 4; ++pass) {
        const int u = t + 256 * pass;           // 1024 tasks: x (64) x oc (16)
        const int x = u >> 4, oc = u & 15;
        uint w[4];
#pragma unroll
        for (int k = 0; k < 4; ++k) {
            const float f0 = tile[(oc * 8 + 2 * k) * 65 + x];
            const float f1 = tile[(oc * 8 + 2 * k + 1) * 65 + x];
            w[k] = (uint)f2bf(f0) | ((uint)f2bf(f1) << 16);
        }
        uint4 o; o.x = w[0]; o.y = w[1]; o.z = w[2]; o.w = w[3];
        *(uint4*)(obase + (size_t)x * 128 + oc * 8) = o;
    }
}

// ---------------- kernel 1: MFMA corr, fragments direct from global ----------------
// Block: 32-wide j tile, 4 corr rows {ybase, +2, +4, +6}, (b,q) XCD-pinned.
// 4 waves = (yrow, p=x-parity); each wave owns rows ybase+2yrow and +4 more.
// Per dyi: <=24 B-frag loads per lane (L2), 24 MFMA, scatter -> ctile[dyi&1],
// ONE barrier, coalesced store. s>36 B columns can never reach a stored
// t<=20 output -> masked (dead-band). OOB rows/cols zero-masked = zero-pad.
__global__ __launch_bounds__(256, 4)
void corr_mfma(const ushort* __restrict__ in1t, const ushort* __restrict__ in2t,
               ushort* __restrict__ corrw) {
    __shared__ ushort ctile[2][21 * 136];   // [slot][t*136 + rr*34 + x], x in [0,32)
    const int tid = threadIdx.x;
    // XCD swizzle: grid (5,20,8)=800 blocks; lin%8 -> z so each XCD owns one (b,q)
    const int lin = blockIdx.x + 5 * (blockIdx.y + 20 * blockIdx.z);
    const int zz = lin & 7;
    const int rem = lin >> 3;               // [0,100)
    const int j0 = (rem % 5) * 32;
    const int ytile = rem / 5;              // [0,20)
    const int b = zz >> 1, q = zz & 1;
    const int ybase = q + 8 * ytile;        // block corr rows ybase+{0,2,4,6}
    const int lane = tid & 63, wav = tid >> 6;
    const int yrow = wav >> 1, p = wav & 1;
    const int mn = lane & 15, quad = lane >> 4;

    // A fragments direct from global: rows ybase+2yrow+4a+17 (a=0,1), col j0+17+2mn+p
    const int ax = j0 + 17 + 2 * mn + p;             // always < 192
    short8 afr[2][4];
#pragma unroll
    for (int a = 0; a < 2; ++a) {
        const int arow = ybase + 2 * yrow + 4 * a + 17;   // <= 176 < 192
        const ushort* aptr = in1t + ((size_t)((b * H_ + arow) * W_ + ax)) * C_ + quad * 8;
#pragma unroll
        for (int kb = 0; kb < 4; ++kb) afr[a][kb] = *(const short8*)(aptr + kb * 32);
    }

    // B base pointers per u3 at dyi=0,a=0: in2t[b, ybY, j0-3+p+2s, c], s = u3*16+mn
    const int ybY = ybase + 2 * yrow - 3;
    const ushort* bptr[3];
    bool colok[3];
#pragma unroll
    for (int u3 = 0; u3 < 3; ++u3) {
        const int s = u3 * 16 + mn;
        const int xp = j0 - 3 + p + 2 * s;
        // OOB col => zero-pad; s>36 can never produce t<=20 => dead band
        colok[u3] = ((unsigned)xp < (unsigned)W_) && (s <= 36);
        bptr[u3] = in2t + (ptrdiff_t)((b * H_ + ybY) * W_ + xp) * C_ + quad * 8;
    }

    const short8 z8 = {0, 0, 0, 0, 0, 0, 0, 0};
    const size_t planebase = (size_t)b * 441;

    for (int dyi = 0; dyi < 21; ++dyi) {
        floatx4 acc[2][3];
#pragma unroll
        for (int a = 0; a < 2; ++a)
#pragma unroll
            for (int u3 = 0; u3 < 3; ++u3) acc[a][u3] = (floatx4){0.f, 0.f, 0.f, 0.f};
#pragma unroll
        for (int a = 0; a < 2; ++a) {
            const int yb = ybY + 2 * dyi + 4 * a;
            if ((unsigned)yb < (unsigned)H_) {          // wave-uniform row mask
                const ptrdiff_t roff = (ptrdiff_t)(2 * dyi + 4 * a) * W_ * C_;
#pragma unroll
                for (int u3 = 0; u3 < 3; ++u3) {
                    short8 b0 = z8, b1 = z8, b2 = z8, b3 = z8;
                    if (colok[u3]) {                    // per-lane mask, loads only
                        const ushort* bp = bptr[u3] + roff;
                        b0 = *(const short8*)(bp);
                        b1 = *(const short8*)(bp + 32);
                        b2 = *(const short8*)(bp + 64);
                        b3 = *(const short8*)(bp + 96);
                    }
                    acc[a][u3] = __builtin_amdgcn_mfma_f32_16x16x32_bf16(afr[a][0], b0, acc[a][u3], 0, 0, 0);
                    acc[a][u3] = __builtin_amdgcn_mfma_f32_16x16x32_bf16(afr[a][1], b1, acc[a][u3], 0, 0, 0);
                    acc[a][u3] = __builtin_amdgcn_mfma_f32_16x16x32_bf16(afr[a][2], b2, acc[a][u3], 0, 0, 0);
                    acc[a][u3] = __builtin_amdgcn_mfma_f32_16x16x32_bf16(afr[a][3], b3, acc[a][u3], 0, 0, 0);
                }
            }
        }

        // scatter C frags: (mr = quad*4+v, s = u3*16+mn) -> t = s-mr, x = 2mr+p
        // row index rr = yrow + 2a  (rr -> corr row ybase + 2rr)
        ushort* ct = &ctile[dyi & 1][0];
#pragma unroll
        for (int a = 0; a < 2; ++a) {
            const int rr = yrow + 2 * a;
#pragma unroll
            for (int u3 = 0; u3 < 3; ++u3) {
#pragma unroll
                for (int v = 0; v < 4; ++v) {
                    const int mr = quad * 4 + v;
                    const int t = u3 * 16 + mn - mr;
                    if (t >= 0 && t <= 20)
                        ct[t * 136 + rr * 34 + 2 * mr + p] = f2bf(acc[a][u3][v]);
                }
            }
        }
        __syncthreads();   // scatter complete; also fences slot reuse (2-apart)
        // coalesced store of corr tile (dword = 2 bf16): 21 t x 4 rows x 16 dwords
#pragma unroll
        for (int it = 0; it < 6; ++it) {
            const int idx = tid + it * 256;
            if (idx < 1344) {
                const int t = idx >> 6, rem2 = idx & 63;
                const int rr = rem2 >> 4, x2 = (rem2 & 15) << 1;
                const uint val = *(const uint*)(ct + t * 136 + rr * 34 + x2);
                const int Y = ybase + 2 * rr, X = j0 + x2;
                if (Y < 158 && X < 158) {
                    const size_t off = ((planebase + (size_t)(dyi * 21 + t)) * 158 + Y) * 158 + X;
                    *(uint*)(corrw + off) = val;
                }
            }
        }
    }
}

// ---------------- kernel 2: 3x3 window sum (16 out rows / block) ----------------
__global__ __launch_bounds__(256)
void window_kernel(const ushort* __restrict__ corrw, float* __restrict__ out) {
    __shared__ uint wsl[1440];   // 18 rows x 80 dwords (160 bf16 cols)
    const int tid = threadIdx.x;
    const int i0 = blockIdx.x * 16;
    const int plane = blockIdx.y;
    const ushort* cp = corrw + (size_t)plane * 24964;
    for (int task = tid; task < 1440; task += 256) {
        const int r = task / 80;
        const int dc = task - r * 80;
        const int row = i0 + r;
        if (dc < 79 && row < 158)
            wsl[task] = *(const uint*)(cp + row * 158 + dc * 2);
    }
    __syncthreads();
    if (tid < 156) {
        const ushort* cl = (const ushort*)wsl;
        float S[18];
#pragma unroll
        for (int r = 0; r < 18; ++r) {
            const ushort* rp = cl + r * 160 + tid;
            S[r] = bf2f(rp[0]) + bf2f(rp[1]) + bf2f(rp[2]);
        }
        const float sc = 1.f / 1152.f;
#pragma unroll
        for (int r = 0; r < 16; ++r) {
            const int row = i0 + r;
            if (row < 156)
                out[(size_t)plane * 24336 + (size_t)row * 156 + tid] =
                    (S[r] + S[r + 1] + S[r + 2]) * sc;
        }
    }
}

// ---------------- fallback (round-1 fp32 kernel) ----------------
#define OUT_HW 156
#define NDISP 21
#define TILE_OUT 14
#define TILE_CORR 16
#define S2W 56
#define NT 256

__global__ __launch_bounds__(NT, 4)
void corr_fallback(const float* __restrict__ in1, const float* __restrict__ in2,
                   float* __restrict__ out) {
    __shared__ float s2s[TILE_CORR * S2W];
    __shared__ float corrs[NDISP * TILE_CORR * TILE_CORR];
    const int tid = threadIdx.x;
    const int tx = tid & 15;
    const int ty = tid >> 4;
    const int tj = blockIdx.x;
    const int ti = blockIdx.y;
    const int z = blockIdx.z;
    const int b = z / NDISP;
    const int dyi = z - b * NDISP;
    const int dy = 2 * dyi - 20;
    const int y0 = ti * TILE_OUT;
    const int x0 = tj * TILE_OUT;
    const int y = y0 + ty;
    const int x = x0 + tx;
    float acc[NDISP];
#pragma unroll
    for (int d = 0; d < NDISP; ++d) acc[d] = 0.f;
    const float* p1 = in1 + (size_t)b * C_ * HW_ + (size_t)(y + 17) * W_ + (x + 17);
    const float* p2base = in2 + (size_t)b * C_ * HW_;
    for (int c = 0; c < C_; ++c) {
        const float a = p1[(size_t)c * HW_];
        const float* p2 = p2base + (size_t)c * HW_;
        for (int idx = tid; idx < TILE_CORR * S2W; idx += NT) {
            const int r = idx / S2W;
            const int cc = idx - r * S2W;
            const int gr = y0 + r + 17 + dy;
            const int gc = x0 + cc - 3;
            float v = 0.f;
            if ((unsigned)gr < H_ && (unsigned)gc < W_) v = p2[gr * W_ + gc];
            s2s[idx] = v;
        }
        __syncthreads();
        const float* srow = &s2s[ty * S2W + tx];
#pragma unroll
        for (int d = 0; d < NDISP; ++d) acc[d] += a * srow[2 * d];
        __syncthreads();
    }
#pragma unroll
    for (int d = 0; d < NDISP; ++d)
        corrs[d * (TILE_CORR * TILE_CORR) + tid] = acc[d];
    __syncthreads();
    const float scale = 1.f / 1152.f;
    for (int o = tid; o < NDISP * TILE_OUT * TILE_OUT; o += NT) {
        const int d = o / (TILE_OUT * TILE_OUT);
        const int rem = o - d * (TILE_OUT * TILE_OUT);
        const int i = rem / TILE_OUT;
        const int j = rem - i * TILE_OUT;
        const float* cpt = &corrs[d * (TILE_CORR * TILE_CORR) + i * TILE_CORR + j];
        const float s = cpt[0] + cpt[1] + cpt[2]
                      + cpt[16] + cpt[17] + cpt[18]
                      + cpt[32] + cpt[33] + cpt[34];
        const int ig = y0 + i;
        const int jg = x0 + j;
        if (ig < OUT_HW && jg < OUT_HW) {
            const size_t oidx = (((size_t)b * (NDISP * NDISP) + (size_t)dyi * NDISP + d)
                                 * OUT_HW + ig) * OUT_HW + jg;
            out[oidx] = s * scale;
        }
    }
}

extern "C" void kernel_launch(void* const* d_in, const int* in_sizes, int n_in,
                              void* d_out, int out_size, void* d_ws, size_t ws_size,
                              hipStream_t stream) {
    const float* in1 = (const float*)d_in[0];
    const float* in2 = (const float*)d_in[1];
    float* out = (float*)d_out;

    if (ws_size >= WS_NEED) {
        ushort* wsp = (ushort*)d_ws;
        ushort* in1t = wsp;
        ushort* in2t = wsp + (size_t)NE_;
        ushort* corrw = wsp + (size_t)2 * NE_;
        cvt_t_kernel<<<dim3(576, 4, 2), 256, 0, stream>>>(in1, in2, wsp);
        corr_mfma<<<dim3(5, 20, 8), 256, 0, stream>>>(in1t, in2t, corrw);
        window_kernel<<<dim3(10, 1764), 256, 0, stream>>>(corrw, out);
    } else {
        corr_fallback<<<dim3(12, 12, 84), 256, 0, stream>>>(in1, in2, out);
    }
}